// Round 2
// baseline (71.952 us; speedup 1.0000x reference)
//
#include <hip/hip_runtime.h>

// Ball query: for each of NQ=32768 query points g (p_grid), find the first
// K=10 indices i (ascending) of x (N2=8192 points) with
//   d2 = (|g|^2 + |x_i|^2) - 2*dot(g, x_i) <= 0.25^2
// Output (concat, float32): mapping [NQ,K] (index as float, 0 if unfound),
//                           points  [NQ,K,3] (x_i coords, 0 if unfound).
//
// R2: pack x -> float4(x,y,z,|x|^2) in d_ws (exact unfused arithmetic, once);
// main kernel = one wave per query, 128 candidates/iter (2x64 ballots),
// software prefetch of the next 128 so load latency overlaps compute.
// Early exit (wave-uniform) once K found.

#define BQ_K   10
#define BQ_N2  8192
#define BQ_NQ  32768
#define BQ_R2  0.0625f

__global__ __launch_bounds__(256) void bq_pack(
    const float* __restrict__ x,   // [N2,3]
    float4* __restrict__ xp)       // [N2] (x,y,z,xx)
{
    const int i = (int)blockIdx.x * 256 + (int)threadIdx.x;
    if (i < BQ_N2) {
        const float xv = x[i * 3 + 0];
        const float yv = x[i * 3 + 1];
        const float zv = x[i * 3 + 2];
        // |x|^2 left-to-right, unfused (matches np.sum(p2*p2, -1) exactly).
        const float xx = __fadd_rn(__fadd_rn(__fmul_rn(xv, xv), __fmul_rn(yv, yv)),
                                   __fmul_rn(zv, zv));
        xp[i] = make_float4(xv, yv, zv, xx);
    }
}

__device__ __forceinline__ float bq_d2(float gg, float gx, float gy, float gz,
                                       const float4& c) {
    // dot(g,x) left-to-right unfused; d2 = (gg + xx) - 2*dot  (reference assoc.)
    const float dt = __fadd_rn(__fadd_rn(__fmul_rn(gx, c.x), __fmul_rn(gy, c.y)),
                               __fmul_rn(gz, c.z));
    return __fsub_rn(__fadd_rn(gg, c.w), __fmul_rn(2.0f, dt));
}

__global__ __launch_bounds__(256) void bq_main(
    const float4* __restrict__ xp,    // [N2] packed
    const float* __restrict__ pg,     // [NQ,3]
    float* __restrict__ map_out,      // [NQ,K]
    float* __restrict__ pts_out)      // [NQ,K,3]
{
    const int lane = threadIdx.x & 63;
    const int q = (int)blockIdx.x * 4 + (threadIdx.x >> 6);   // wave per query

    const float gx = pg[q * 3 + 0];
    const float gy = pg[q * 3 + 1];
    const float gz = pg[q * 3 + 2];
    const float gg = __fadd_rn(__fadd_rn(__fmul_rn(gx, gx), __fmul_rn(gy, gy)),
                               __fmul_rn(gz, gz));

    float* __restrict__ mo = map_out + (size_t)q * BQ_K;
    float* __restrict__ po = pts_out + (size_t)q * BQ_K * 3;

    const unsigned long long lt = (1ull << lane) - 1ull;  // lanes below me

    // Prime the pipeline: first 128 candidates in registers.
    float4 c0 = xp[lane];
    float4 c1 = xp[64 + lane];

    int found = 0;   // wave-uniform count of valid points seen so far

    for (int base = 0; base < BQ_N2; base += 128) {
        // Prefetch next 128 candidates (overlaps with compute below).
        float4 n0, n1;
        const bool more = (base + 128) < BQ_N2;
        if (more) {
            n0 = xp[base + 128 + lane];
            n1 = xp[base + 192 + lane];
        }

        const float d2a = bq_d2(gg, gx, gy, gz, c0);
        const float d2b = bq_d2(gg, gx, gy, gz, c1);
        const bool va = (d2a <= BQ_R2);
        const bool vb = (d2b <= BQ_R2);
        const unsigned long long m0 = __ballot(va);
        const unsigned long long m1 = __ballot(vb);

        if ((m0 | m1) != 0ull) {
            if (va) {
                const int slot = found + __popcll(m0 & lt);
                if (slot < BQ_K) {
                    mo[slot] = (float)(base + lane);
                    po[slot * 3 + 0] = c0.x;
                    po[slot * 3 + 1] = c0.y;
                    po[slot * 3 + 2] = c0.z;
                }
            }
            const int f1 = found + __popcll(m0);
            if (vb) {
                const int slot = f1 + __popcll(m1 & lt);
                if (slot < BQ_K) {
                    mo[slot] = (float)(base + 64 + lane);
                    po[slot * 3 + 0] = c1.x;
                    po[slot * 3 + 1] = c1.y;
                    po[slot * 3 + 2] = c1.z;
                }
            }
            found = f1 + __popcll(m1);
            if (found >= BQ_K) break;                 // uniform early exit
        }

        if (more) { c0 = n0; c1 = n1; }
    }

    // Zero-fill unfound slots (d_out is poisoned 0xAA before every launch).
    const int filled = found < BQ_K ? found : BQ_K;
    if (lane < BQ_K && lane >= filled) {
        mo[lane] = 0.0f;
        po[lane * 3 + 0] = 0.0f;
        po[lane * 3 + 1] = 0.0f;
        po[lane * 3 + 2] = 0.0f;
    }
}

extern "C" void kernel_launch(void* const* d_in, const int* in_sizes, int n_in,
                              void* d_out, int out_size, void* d_ws, size_t ws_size,
                              hipStream_t stream) {
    const float* x  = (const float*)d_in[0];   // (1, 8192, 3) float32
    const float* pg = (const float*)d_in[1];   // (1, 64, 32, 16, 3) float32
    float* out = (float*)d_out;
    float* map_out = out;                          // [NQ*K]
    float* pts_out = out + (size_t)BQ_NQ * BQ_K;   // [NQ*K*3]
    float4* xp = (float4*)d_ws;                    // 8192 * 16 B = 128 KB

    bq_pack<<<(BQ_N2 + 255) / 256, 256, 0, stream>>>(x, xp);
    bq_main<<<BQ_NQ / 4, 256, 0, stream>>>(xp, pg, map_out, pts_out);
}

// Round 3
// 70.912 us; speedup vs baseline: 1.0147x; 1.0147x over previous
//
#include <hip/hip_runtime.h>

// Ball query: for each of NQ=32768 query points g (p_grid), find the first
// K=10 indices i (ascending) of x (N2=8192 points) with
//   d2 = (|g|^2 + |x_i|^2) - 2*dot(g, x_i) <= 0.25^2
// Output (concat, float32): mapping [NQ,K] (index as float, 0 if unfound),
//                           points  [NQ,K,3] (x_i coords, 0 if unfound).
//
// R3: single kernel, NO d_ws (R2's d_ws round-trip cost bit-exactness:
// absmax 0 -> 16). One wave per query; 256 candidates/iter (4x64 ballots)
// with register prefetch of the next 256; wave-uniform early exit at K.
// Exact-FP32 (unfused, left-to-right) distance matches the numpy reference
// bit-for-bit at the radius boundary (absmax was 0.0 with this arithmetic).

#define BQ_K   10
#define BQ_N2  8192
#define BQ_NQ  32768
#define BQ_R2  0.0625f

__device__ __forceinline__ float bq_d2(float gg, float gx, float gy, float gz,
                                       float xv, float yv, float zv) {
    // |x|^2 and dot(g,x) left-to-right, unfused; d2 = (gg + xx) - 2*dot
    // (exactly the reference's association).
    const float xx = __fadd_rn(__fadd_rn(__fmul_rn(xv, xv), __fmul_rn(yv, yv)),
                               __fmul_rn(zv, zv));
    const float dt = __fadd_rn(__fadd_rn(__fmul_rn(gx, xv), __fmul_rn(gy, yv)),
                               __fmul_rn(gz, zv));
    return __fsub_rn(__fadd_rn(gg, xx), __fmul_rn(2.0f, dt));
}

__global__ __launch_bounds__(256) void bq_kernel(
    const float* __restrict__ x,      // [N2,3]
    const float* __restrict__ pg,     // [NQ,3]
    float* __restrict__ map_out,      // [NQ,K]
    float* __restrict__ pts_out)      // [NQ,K,3]
{
    const int lane = threadIdx.x & 63;
    const int q = (int)blockIdx.x * 4 + (threadIdx.x >> 6);   // wave per query

    const float gx = pg[q * 3 + 0];
    const float gy = pg[q * 3 + 1];
    const float gz = pg[q * 3 + 2];
    const float gg = __fadd_rn(__fadd_rn(__fmul_rn(gx, gx), __fmul_rn(gy, gy)),
                               __fmul_rn(gz, gz));

    float* __restrict__ mo = map_out + (size_t)q * BQ_K;
    float* __restrict__ po = pts_out + (size_t)q * BQ_K * 3;
    const unsigned long long lt = (1ull << lane) - 1ull;   // lanes below me

    // Prime: first 256 candidates in registers (4 sub-chunks of 64).
    float cx[4], cy[4], cz[4];
    #pragma unroll
    for (int s = 0; s < 4; ++s) {
        const int i = (s * 64 + lane) * 3;
        cx[s] = x[i]; cy[s] = x[i + 1]; cz[s] = x[i + 2];
    }

    int found = 0;   // wave-uniform count of valid points seen so far

    for (int base = 0; base < BQ_N2; base += 256) {
        // Prefetch next 256 candidates (overlaps load latency with compute).
        float nx_[4], ny_[4], nz_[4];
        const bool more = (base + 256) < BQ_N2;
        if (more) {
            #pragma unroll
            for (int s = 0; s < 4; ++s) {
                const int i = (base + 256 + s * 64 + lane) * 3;
                nx_[s] = x[i]; ny_[s] = x[i + 1]; nz_[s] = x[i + 2];
            }
        }

        bool v[4];
        unsigned long long m[4];
        #pragma unroll
        for (int s = 0; s < 4; ++s) {
            const float d2 = bq_d2(gg, gx, gy, gz, cx[s], cy[s], cz[s]);
            v[s] = (d2 <= BQ_R2);
            m[s] = __ballot(v[s]);
        }

        if ((m[0] | m[1] | m[2] | m[3]) != 0ull) {
            int f = found;
            #pragma unroll
            for (int s = 0; s < 4; ++s) {
                if (v[s]) {
                    const int slot = f + __popcll(m[s] & lt);
                    if (slot < BQ_K) {
                        mo[slot] = (float)(base + s * 64 + lane);
                        po[slot * 3 + 0] = cx[s];
                        po[slot * 3 + 1] = cy[s];
                        po[slot * 3 + 2] = cz[s];
                    }
                }
                f += __popcll(m[s]);
            }
            found = f;
            if (found >= BQ_K) break;                 // uniform early exit
        }

        if (more) {
            #pragma unroll
            for (int s = 0; s < 4; ++s) {
                cx[s] = nx_[s]; cy[s] = ny_[s]; cz[s] = nz_[s];
            }
        }
    }

    // Zero-fill unfound slots (d_out is poisoned 0xAA before every launch).
    const int filled = found < BQ_K ? found : BQ_K;
    if (lane < BQ_K && lane >= filled) {
        mo[lane] = 0.0f;
        po[lane * 3 + 0] = 0.0f;
        po[lane * 3 + 1] = 0.0f;
        po[lane * 3 + 2] = 0.0f;
    }
}

extern "C" void kernel_launch(void* const* d_in, const int* in_sizes, int n_in,
                              void* d_out, int out_size, void* d_ws, size_t ws_size,
                              hipStream_t stream) {
    const float* x  = (const float*)d_in[0];   // (1, 8192, 3) float32
    const float* pg = (const float*)d_in[1];   // (1, 64, 32, 16, 3) float32
    float* out = (float*)d_out;
    float* map_out = out;                          // [NQ*K]
    float* pts_out = out + (size_t)BQ_NQ * BQ_K;   // [NQ*K*3]

    // One wave per query: 32768 queries / 4 waves per 256-thread block.
    bq_kernel<<<BQ_NQ / 4, 256, 0, stream>>>(x, pg, map_out, pts_out);
}